// Round 2
// baseline (290.597 us; speedup 1.0000x reference)
//
#include <hip/hip_runtime.h>
#include <hip/hip_bf16.h>
#include <math.h>

// HyperbolicMLR: out[b,c] = -asinh( 2*sc_diff_a / ((1+diff_norm2)*|a_c|) )
// with px = <x_proj_b, p_c>, xa = <x_proj_b, a_c> via bf16 MFMA GEMMs.
// R2: double-buffered 2-phase pipeline (prefetch next K-tile before compute).

#define EPSF 1e-15f
#define MAXN 0.99999f   // (1 - 1e-5) / sqrt(c), c = 1

constexpr int Bdim = 4096;
constexpr int Ddim = 1024;
constexpr int Cdim = 4096;

typedef __bf16 bf16x8 __attribute__((ext_vector_type(8)));
typedef float  f32x4  __attribute__((ext_vector_type(4)));
typedef unsigned short u16;

__device__ __forceinline__ u16 f2bf(float f) {
  __hip_bfloat16 h = __float2bfloat16(f);   // RNE
  return *reinterpret_cast<const u16*>(&h);
}

__device__ __forceinline__ void gl_lds16(const u16* g, u16* l) {
  __builtin_amdgcn_global_load_lds(
      (const __attribute__((address_space(1))) void*)g,
      (__attribute__((address_space(3))) void*)l, 16, 0, 0);
}

// ---------------- prep kernels ----------------

__global__ __launch_bounds__(256) void prep_x(const float* __restrict__ x,
                                              u16* __restrict__ xb,
                                              float* __restrict__ x2o) {
  const int b = blockIdx.x, t = threadIdx.x;
  float4 v = ((const float4*)(x + (size_t)b * Ddim))[t];
  float s = v.x * v.x + v.y * v.y + v.z * v.z + v.w * v.w;
  __shared__ float red[4];
#pragma unroll
  for (int o = 32; o > 0; o >>= 1) s += __shfl_down(s, o);
  if ((t & 63) == 0) red[t >> 6] = s;
  __syncthreads();
  s = red[0] + red[1] + red[2] + red[3];
  float norm  = sqrtf(s);
  float xn    = fmaxf(norm, EPSF);
  float scale = (xn > MAXN) ? (MAXN / xn) : 1.0f;
  if (t == 0) x2o[b] = s * scale * scale;
  ushort4 o4;
  o4.x = f2bf(v.x * scale); o4.y = f2bf(v.y * scale);
  o4.z = f2bf(v.z * scale); o4.w = f2bf(v.w * scale);
  ((ushort4*)(xb + (size_t)b * Ddim))[t] = o4;
}

__global__ __launch_bounds__(256) void prep_pa(const float* __restrict__ a,
                                               const float* __restrict__ p,
                                               u16* __restrict__ ab,
                                               u16* __restrict__ pbuf,
                                               float* __restrict__ p2o,
                                               float* __restrict__ pao,
                                               float* __restrict__ ano) {
  const int c = blockIdx.x, t = threadIdx.x;
  float4 av = ((const float4*)(a + (size_t)c * Ddim))[t];
  float4 pv = ((const float4*)(p + (size_t)c * Ddim))[t];
  float sp2 = pv.x * pv.x + pv.y * pv.y + pv.z * pv.z + pv.w * pv.w;
  float spa = pv.x * av.x + pv.y * av.y + pv.z * av.z + pv.w * av.w;
  float sa2 = av.x * av.x + av.y * av.y + av.z * av.z + av.w * av.w;
  __shared__ float red[12];
#pragma unroll
  for (int o = 32; o > 0; o >>= 1) {
    sp2 += __shfl_down(sp2, o);
    spa += __shfl_down(spa, o);
    sa2 += __shfl_down(sa2, o);
  }
  if ((t & 63) == 0) { int w = t >> 6; red[w] = sp2; red[4 + w] = spa; red[8 + w] = sa2; }
  __syncthreads();
  if (t == 0) {
    p2o[c] = red[0] + red[1] + red[2] + red[3];
    pao[c] = red[4] + red[5] + red[6] + red[7];
    ano[c] = sqrtf(red[8] + red[9] + red[10] + red[11]);
  }
  ushort4 oa, op;
  oa.x = f2bf(av.x); oa.y = f2bf(av.y); oa.z = f2bf(av.z); oa.w = f2bf(av.w);
  op.x = f2bf(pv.x); op.y = f2bf(pv.y); op.z = f2bf(pv.z); op.w = f2bf(pv.w);
  ((ushort4*)(ab   + (size_t)c * Ddim))[t] = oa;
  ((ushort4*)(pbuf + (size_t)c * Ddim))[t] = op;
}

// ---------------- fused dual-GEMM + epilogue ----------------
// 128x128 tile, BK=32, 4 waves (2x2 of 64x64), double-buffered 2-phase loop.

__global__ __launch_bounds__(256) void gemm_ep(
    const u16* __restrict__ xb, const u16* __restrict__ pb,
    const u16* __restrict__ ab, const float* __restrict__ x2g,
    const float* __restrict__ p2g, const float* __restrict__ pag,
    const float* __restrict__ ang, float* __restrict__ out) {
  __shared__ u16 Xs[2][4096];   // [buf][128 rows x 32 k]
  __shared__ u16 Ps[2][4096];
  __shared__ u16 As[2][4096];
  __shared__ float x2s[128], p2s[128], pas[128], ans[128];

  const int t = threadIdx.x;
  const int rowBase = blockIdx.y * 128;
  const int colBase = blockIdx.x * 128;

  if (t < 128) {
    x2s[t] = x2g[rowBase + t];
    p2s[t] = p2g[colBase + t];
    pas[t] = pag[colBase + t];
    ans[t] = ang[colBase + t];
  }

  const int lane = t & 63;
  const int wid  = t >> 6;
  const int wr   = wid >> 1;     // wave row 0..1
  const int wc   = wid & 1;      // wave col 0..1

  // staging: thread t covers 16B chunk t (rows 0..63) and chunk 256+t (rows 64..127)
  const int rx0 = t >> 2;
  const int kk  = (t & 3) * 8;
  const u16* xp0 = xb + (size_t)(rowBase + rx0) * Ddim + kk;
  const u16* pp0 = pb + (size_t)(colBase + rx0) * Ddim + kk;
  const u16* ap0 = ab + (size_t)(colBase + rx0) * Ddim + kk;
  const size_t half = (size_t)64 * Ddim;
  const int d0 = t * 8;          // u16 offset of this thread's 16B slot
  const int d1 = 2048 + t * 8;

  // fragment LDS offsets (ushort units)
  const int abase = (wr * 64 + (lane & 15)) * 32 + (lane >> 4) * 8;
  const int bbase = (wc * 64 + (lane & 15)) * 32 + (lane >> 4) * 8;

  f32x4 accP[4][4], accA[4][4];
  const f32x4 zero = {0.f, 0.f, 0.f, 0.f};
#pragma unroll
  for (int m = 0; m < 4; ++m)
#pragma unroll
    for (int n = 0; n < 4; ++n) { accP[m][n] = zero; accA[m][n] = zero; }

#define STAGE(buf, kt2) do {                                     \
    const size_t go = (size_t)(kt2) * 32;                        \
    gl_lds16(xp0 + go,        &Xs[buf][d0]);                     \
    gl_lds16(xp0 + half + go, &Xs[buf][d1]);                     \
    gl_lds16(pp0 + go,        &Ps[buf][d0]);                     \
    gl_lds16(pp0 + half + go, &Ps[buf][d1]);                     \
    gl_lds16(ap0 + go,        &As[buf][d0]);                     \
    gl_lds16(ap0 + half + go, &As[buf][d1]);                     \
  } while (0)

#define COMPUTE(buf) do {                                        \
    bf16x8 av[4], bp[4], ba[4];                                  \
    _Pragma("unroll")                                            \
    for (int m = 0; m < 4; ++m)                                  \
      av[m] = *(const bf16x8*)&Xs[buf][abase + m * 512];         \
    _Pragma("unroll")                                            \
    for (int n = 0; n < 4; ++n) {                                \
      bp[n] = *(const bf16x8*)&Ps[buf][bbase + n * 512];         \
      ba[n] = *(const bf16x8*)&As[buf][bbase + n * 512];         \
    }                                                            \
    _Pragma("unroll")                                            \
    for (int m = 0; m < 4; ++m)                                  \
      _Pragma("unroll")                                          \
      for (int n = 0; n < 4; ++n) {                              \
        accP[m][n] = __builtin_amdgcn_mfma_f32_16x16x32_bf16(av[m], bp[n], accP[m][n], 0, 0, 0); \
        accA[m][n] = __builtin_amdgcn_mfma_f32_16x16x32_bf16(av[m], ba[n], accA[m][n], 0, 0, 0); \
      }                                                          \
  } while (0)

  // prologue: fill buffer 0
  STAGE(0, 0);
  __syncthreads();               // drains vmcnt(0)+lgkmcnt(0), then barrier

  int cur = 0;
  for (int kt = 0; kt < Ddim / 32 - 1; ++kt) {
    STAGE(cur ^ 1, kt + 1);      // issue next-tile loads FIRST (overlap with compute)
    COMPUTE(cur);
    __syncthreads();             // next tile staged + everyone done reading cur
    cur ^= 1;
  }
  COMPUTE(cur);                  // last tile, no prefetch

#undef STAGE
#undef COMPUTE

  // epilogue: C/D layout col = lane&15, row = (lane>>4)*4 + j
#pragma unroll
  for (int m = 0; m < 4; ++m) {
    const int rl0 = wr * 64 + m * 16 + (lane >> 4) * 4;
#pragma unroll
    for (int n = 0; n < 4; ++n) {
      const int cl  = wc * 64 + n * 16 + (lane & 15);
      const float p2c = p2s[cl], pac = pas[cl], anc = ans[cl];
      const float Bcc = 1.0f - p2c;
      f32x4 px4 = accP[m][n];
      f32x4 xa4 = accA[m][n];
#pragma unroll
      for (int j = 0; j < 4; ++j) {
        const float x2r = x2s[rl0 + j];
        const float px = px4[j];
        const float xa = xa4[j];
        const float Av  = 1.0f - 2.0f * px + x2r;
        const float den = fmaxf(1.0f - 2.0f * px + x2r * p2c, EPSF);
        const float dn2 = fmaxf((Av * Av * p2c + Bcc * Bcc * x2r - 2.0f * Av * Bcc * px) / (den * den), EPSF);
        const float sc  = (Bcc * xa - Av * pac) / den;
        const float dv  = fmaxf((1.0f + dn2) * anc, EPSF);   // always positive
        const float z   = (2.0f * sc) / dv;
        out[(size_t)(rowBase + rl0 + j) * Cdim + (colBase + cl)] = -asinhf(z);
      }
    }
  }
}

extern "C" void kernel_launch(void* const* d_in, const int* in_sizes, int n_in,
                              void* d_out, int out_size, void* d_ws, size_t ws_size,
                              hipStream_t stream) {
  const float* x = (const float*)d_in[0];
  const float* a = (const float*)d_in[1];
  const float* p = (const float*)d_in[2];
  float* out = (float*)d_out;

  char* ws = (char*)d_ws;
  u16* xb = (u16*)(ws);                                   // 8 MiB
  u16* pb = (u16*)(ws + (size_t)8 * 1024 * 1024);         // 8 MiB
  u16* ab = (u16*)(ws + (size_t)16 * 1024 * 1024);        // 8 MiB
  float* x2 = (float*)(ws + (size_t)24 * 1024 * 1024);    // 16 KiB
  float* p2 = x2 + Bdim;
  float* pa = p2 + Cdim;
  float* an = pa + Cdim;

  prep_x <<<Bdim, 256, 0, stream>>>(x, xb, x2);
  prep_pa<<<Cdim, 256, 0, stream>>>(a, p, ab, pb, p2, pa, an);
  gemm_ep<<<dim3(Cdim / 128, Bdim / 128), 256, 0, stream>>>(xb, pb, ab, x2, p2, pa, an, out);
}

// Round 3
// 166.410 us; speedup vs baseline: 1.7463x; 1.7463x over previous
//
#include <hip/hip_runtime.h>
#include <hip/hip_bf16.h>
#include <math.h>

// HyperbolicMLR: out[b,c] = -asinh( 2*sc_diff_a / ((1+diff_norm2)*|a_c|) )
// with px = <x_proj_b, p_c>, xa = <x_proj_b, a_c> via bf16 MFMA GEMMs.
// R3: single-buffer m97 loop + register diet (__launch_bounds__(256,2)) so
// acc(128 AGPR) + arch VGPR <= 256 -> 2 waves/SIMD -> 2 blocks/CU overlap.

#define EPSF 1e-15f
#define MAXN 0.99999f   // (1 - 1e-5) / sqrt(c), c = 1

constexpr int Bdim = 4096;
constexpr int Ddim = 1024;
constexpr int Cdim = 4096;

typedef __bf16 bf16x8 __attribute__((ext_vector_type(8)));
typedef float  f32x4  __attribute__((ext_vector_type(4)));
typedef unsigned short u16;

__device__ __forceinline__ u16 f2bf(float f) {
  __hip_bfloat16 h = __float2bfloat16(f);   // RNE
  return *reinterpret_cast<const u16*>(&h);
}

__device__ __forceinline__ void gl_lds16(const u16* g, u16* l) {
  __builtin_amdgcn_global_load_lds(
      (const __attribute__((address_space(1))) void*)g,
      (__attribute__((address_space(3))) void*)l, 16, 0, 0);
}

// ---------------- prep kernels ----------------

__global__ __launch_bounds__(256) void prep_x(const float* __restrict__ x,
                                              u16* __restrict__ xb,
                                              float* __restrict__ x2o) {
  const int b = blockIdx.x, t = threadIdx.x;
  float4 v = ((const float4*)(x + (size_t)b * Ddim))[t];
  float s = v.x * v.x + v.y * v.y + v.z * v.z + v.w * v.w;
  __shared__ float red[4];
#pragma unroll
  for (int o = 32; o > 0; o >>= 1) s += __shfl_down(s, o);
  if ((t & 63) == 0) red[t >> 6] = s;
  __syncthreads();
  s = red[0] + red[1] + red[2] + red[3];
  float norm  = sqrtf(s);
  float xn    = fmaxf(norm, EPSF);
  float scale = (xn > MAXN) ? (MAXN / xn) : 1.0f;
  if (t == 0) x2o[b] = s * scale * scale;
  ushort4 o4;
  o4.x = f2bf(v.x * scale); o4.y = f2bf(v.y * scale);
  o4.z = f2bf(v.z * scale); o4.w = f2bf(v.w * scale);
  ((ushort4*)(xb + (size_t)b * Ddim))[t] = o4;
}

__global__ __launch_bounds__(256) void prep_pa(const float* __restrict__ a,
                                               const float* __restrict__ p,
                                               u16* __restrict__ ab,
                                               u16* __restrict__ pbuf,
                                               float* __restrict__ p2o,
                                               float* __restrict__ pao,
                                               float* __restrict__ ano) {
  const int c = blockIdx.x, t = threadIdx.x;
  float4 av = ((const float4*)(a + (size_t)c * Ddim))[t];
  float4 pv = ((const float4*)(p + (size_t)c * Ddim))[t];
  float sp2 = pv.x * pv.x + pv.y * pv.y + pv.z * pv.z + pv.w * pv.w;
  float spa = pv.x * av.x + pv.y * av.y + pv.z * av.z + pv.w * av.w;
  float sa2 = av.x * av.x + av.y * av.y + av.z * av.z + av.w * av.w;
  __shared__ float red[12];
#pragma unroll
  for (int o = 32; o > 0; o >>= 1) {
    sp2 += __shfl_down(sp2, o);
    spa += __shfl_down(spa, o);
    sa2 += __shfl_down(sa2, o);
  }
  if ((t & 63) == 0) { int w = t >> 6; red[w] = sp2; red[4 + w] = spa; red[8 + w] = sa2; }
  __syncthreads();
  if (t == 0) {
    p2o[c] = red[0] + red[1] + red[2] + red[3];
    pao[c] = red[4] + red[5] + red[6] + red[7];
    ano[c] = sqrtf(red[8] + red[9] + red[10] + red[11]);
  }
  ushort4 oa, op;
  oa.x = f2bf(av.x); oa.y = f2bf(av.y); oa.z = f2bf(av.z); oa.w = f2bf(av.w);
  op.x = f2bf(pv.x); op.y = f2bf(pv.y); op.z = f2bf(pv.z); op.w = f2bf(pv.w);
  ((ushort4*)(ab   + (size_t)c * Ddim))[t] = oa;
  ((ushort4*)(pbuf + (size_t)c * Ddim))[t] = op;
}

// ---------------- fused dual-GEMM + epilogue ----------------
// 128x128 tile, BK=32, 4 waves (2x2 of 64x64), single-buffer loop.
// __launch_bounds__(256,2): cap total regs/wave at 256 (128 acc + <=128 arch)
// so 2 blocks/CU co-reside and overlap stage/compute phases (m97 mechanism).

__global__ __launch_bounds__(256, 2) void gemm_ep(
    const u16* __restrict__ xb, const u16* __restrict__ pb,
    const u16* __restrict__ ab, const float* __restrict__ x2g,
    const float* __restrict__ p2g, const float* __restrict__ pag,
    const float* __restrict__ ang, float* __restrict__ out) {
  __shared__ u16 Xs[4096];   // 128 rows x 32 k
  __shared__ u16 Ps[4096];
  __shared__ u16 As[4096];
  __shared__ float x2s[128], p2s[128], pas[128], ans[128];

  const int t = threadIdx.x;
  const int rowBase = blockIdx.y * 128;
  const int colBase = blockIdx.x * 128;

  if (t < 128) {
    x2s[t] = x2g[rowBase + t];
    p2s[t] = p2g[colBase + t];
    pas[t] = pag[colBase + t];
    ans[t] = ang[colBase + t];
  }

  const int lane = t & 63;
  const int wid  = t >> 6;
  const int wr   = wid >> 1;     // wave row 0..1
  const int wc   = wid & 1;      // wave col 0..1

  // staging: thread t covers 16B chunk t (rows 0..63) and chunk 256+t (rows 64..127)
  const int rx0 = t >> 2;
  const int kk  = (t & 3) * 8;
  const u16* xg = xb + (size_t)(rowBase + rx0) * Ddim + kk;
  const u16* pg = pb + (size_t)(colBase + rx0) * Ddim + kk;
  const u16* ag = ab + (size_t)(colBase + rx0) * Ddim + kk;
  const size_t half = (size_t)64 * Ddim;
  u16* lx0 = &Xs[t * 8]; u16* lx1 = &Xs[2048 + t * 8];
  u16* lp0 = &Ps[t * 8]; u16* lp1 = &Ps[2048 + t * 8];
  u16* la0 = &As[t * 8]; u16* la1 = &As[2048 + t * 8];

  // fragment LDS offsets (ushort units)
  const int afrag = (wr * 64 + (lane & 15)) * 32 + (lane >> 4) * 8;
  const int bfrag = (wc * 64 + (lane & 15)) * 32 + (lane >> 4) * 8;

  f32x4 accP[4][4], accA[4][4];
  const f32x4 zero = {0.f, 0.f, 0.f, 0.f};
#pragma unroll
  for (int m = 0; m < 4; ++m)
#pragma unroll
    for (int n = 0; n < 4; ++n) { accP[m][n] = zero; accA[m][n] = zero; }

  for (int kt = 0; kt < Ddim / 32; ++kt) {
    gl_lds16(xg, lx0); gl_lds16(xg + half, lx1);
    gl_lds16(pg, lp0); gl_lds16(pg + half, lp1);
    gl_lds16(ag, la0); gl_lds16(ag + half, la1);
    xg += 32; pg += 32; ag += 32;
    __syncthreads();   // drains vmcnt(0), then barrier

    bf16x8 bp[4], ba[4];
#pragma unroll
    for (int n = 0; n < 4; ++n) {
      bp[n] = *(const bf16x8*)&Ps[bfrag + n * 512];
      ba[n] = *(const bf16x8*)&As[bfrag + n * 512];
    }
#pragma unroll
    for (int m = 0; m < 4; ++m) {
      bf16x8 av = *(const bf16x8*)&Xs[afrag + m * 512];
#pragma unroll
      for (int n = 0; n < 4; ++n) {
        accP[m][n] = __builtin_amdgcn_mfma_f32_16x16x32_bf16(av, bp[n], accP[m][n], 0, 0, 0);
        accA[m][n] = __builtin_amdgcn_mfma_f32_16x16x32_bf16(av, ba[n], accA[m][n], 0, 0, 0);
      }
    }
    __syncthreads();
  }

  // epilogue: C/D layout col = lane&15, row = (lane>>4)*4 + j
#pragma unroll
  for (int m = 0; m < 4; ++m) {
    const int rl0 = wr * 64 + m * 16 + (lane >> 4) * 4;
#pragma unroll
    for (int n = 0; n < 4; ++n) {
      const int cl  = wc * 64 + n * 16 + (lane & 15);
      const float p2c = p2s[cl], pac = pas[cl], anc = ans[cl];
      const float Bcc = 1.0f - p2c;
      f32x4 px4 = accP[m][n];
      f32x4 xa4 = accA[m][n];
#pragma unroll
      for (int j = 0; j < 4; ++j) {
        const float x2r = x2s[rl0 + j];
        const float px = px4[j];
        const float xa = xa4[j];
        const float Av  = 1.0f - 2.0f * px + x2r;
        const float den = fmaxf(1.0f - 2.0f * px + x2r * p2c, EPSF);
        const float dn2 = fmaxf((Av * Av * p2c + Bcc * Bcc * x2r - 2.0f * Av * Bcc * px) / (den * den), EPSF);
        const float sc  = (Bcc * xa - Av * pac) / den;
        const float dv  = fmaxf((1.0f + dn2) * anc, EPSF);   // always positive
        const float z   = (2.0f * sc) / dv;
        out[(size_t)(rowBase + rl0 + j) * Cdim + (colBase + cl)] = -asinhf(z);
      }
    }
  }
}

extern "C" void kernel_launch(void* const* d_in, const int* in_sizes, int n_in,
                              void* d_out, int out_size, void* d_ws, size_t ws_size,
                              hipStream_t stream) {
  const float* x = (const float*)d_in[0];
  const float* a = (const float*)d_in[1];
  const float* p = (const float*)d_in[2];
  float* out = (float*)d_out;

  char* ws = (char*)d_ws;
  u16* xb = (u16*)(ws);                                   // 8 MiB
  u16* pb = (u16*)(ws + (size_t)8 * 1024 * 1024);         // 8 MiB
  u16* ab = (u16*)(ws + (size_t)16 * 1024 * 1024);        // 8 MiB
  float* x2 = (float*)(ws + (size_t)24 * 1024 * 1024);    // 16 KiB
  float* p2 = x2 + Bdim;
  float* pa = p2 + Cdim;
  float* an = pa + Cdim;

  prep_x <<<Bdim, 256, 0, stream>>>(x, xb, x2);
  prep_pa<<<Cdim, 256, 0, stream>>>(a, p, ab, pb, p2, pa, an);
  gemm_ep<<<dim3(Cdim / 128, Bdim / 128), 256, 0, stream>>>(xb, pb, ab, x2, p2, pa, an, out);
}

// Round 4
// 164.964 us; speedup vs baseline: 1.7616x; 1.0088x over previous
//
#include <hip/hip_runtime.h>
#include <hip/hip_bf16.h>
#include <math.h>

// HyperbolicMLR: out[b,c] = -asinh( 2*sc_diff_a / ((1+diff_norm2)*|a_c|) )
// with px = <x_proj_b, p_c>, xa = <x_proj_b, a_c> via bf16 MFMA GEMMs.
// R4: counted-vmcnt depth-2 pipeline (T4) + XOR LDS swizzle via pre-swizzled
// global source (T2, rule 21) + setprio around MFMA (T5).

#define EPSF 1e-15f
#define MAXN 0.99999f   // (1 - 1e-5) / sqrt(c), c = 1

constexpr int Bdim = 4096;
constexpr int Ddim = 1024;
constexpr int Cdim = 4096;

typedef __bf16 bf16x8 __attribute__((ext_vector_type(8)));
typedef float  f32x4  __attribute__((ext_vector_type(4)));
typedef unsigned short u16;

__device__ __forceinline__ u16 f2bf(float f) {
  __hip_bfloat16 h = __float2bfloat16(f);   // RNE
  return *reinterpret_cast<const u16*>(&h);
}

__device__ __forceinline__ void gl_lds16(const u16* g, u16* l) {
  __builtin_amdgcn_global_load_lds(
      (const __attribute__((address_space(1))) void*)g,
      (__attribute__((address_space(3))) void*)l, 16, 0, 0);
}

// ---------------- prep kernels ----------------

__global__ __launch_bounds__(256) void prep_x(const float* __restrict__ x,
                                              u16* __restrict__ xb,
                                              float* __restrict__ x2o) {
  const int b = blockIdx.x, t = threadIdx.x;
  float4 v = ((const float4*)(x + (size_t)b * Ddim))[t];
  float s = v.x * v.x + v.y * v.y + v.z * v.z + v.w * v.w;
  __shared__ float red[4];
#pragma unroll
  for (int o = 32; o > 0; o >>= 1) s += __shfl_down(s, o);
  if ((t & 63) == 0) red[t >> 6] = s;
  __syncthreads();
  s = red[0] + red[1] + red[2] + red[3];
  float norm  = sqrtf(s);
  float xn    = fmaxf(norm, EPSF);
  float scale = (xn > MAXN) ? (MAXN / xn) : 1.0f;
  if (t == 0) x2o[b] = s * scale * scale;
  ushort4 o4;
  o4.x = f2bf(v.x * scale); o4.y = f2bf(v.y * scale);
  o4.z = f2bf(v.z * scale); o4.w = f2bf(v.w * scale);
  ((ushort4*)(xb + (size_t)b * Ddim))[t] = o4;
}

__global__ __launch_bounds__(256) void prep_pa(const float* __restrict__ a,
                                               const float* __restrict__ p,
                                               u16* __restrict__ ab,
                                               u16* __restrict__ pbuf,
                                               float* __restrict__ p2o,
                                               float* __restrict__ pao,
                                               float* __restrict__ ano) {
  const int c = blockIdx.x, t = threadIdx.x;
  float4 av = ((const float4*)(a + (size_t)c * Ddim))[t];
  float4 pv = ((const float4*)(p + (size_t)c * Ddim))[t];
  float sp2 = pv.x * pv.x + pv.y * pv.y + pv.z * pv.z + pv.w * pv.w;
  float spa = pv.x * av.x + pv.y * av.y + pv.z * av.z + pv.w * av.w;
  float sa2 = av.x * av.x + av.y * av.y + av.z * av.z + av.w * av.w;
  __shared__ float red[12];
#pragma unroll
  for (int o = 32; o > 0; o >>= 1) {
    sp2 += __shfl_down(sp2, o);
    spa += __shfl_down(spa, o);
    sa2 += __shfl_down(sa2, o);
  }
  if ((t & 63) == 0) { int w = t >> 6; red[w] = sp2; red[4 + w] = spa; red[8 + w] = sa2; }
  __syncthreads();
  if (t == 0) {
    p2o[c] = red[0] + red[1] + red[2] + red[3];
    pao[c] = red[4] + red[5] + red[6] + red[7];
    ano[c] = sqrtf(red[8] + red[9] + red[10] + red[11]);
  }
  ushort4 oa, op;
  oa.x = f2bf(av.x); oa.y = f2bf(av.y); oa.z = f2bf(av.z); oa.w = f2bf(av.w);
  op.x = f2bf(pv.x); op.y = f2bf(pv.y); op.z = f2bf(pv.z); op.w = f2bf(pv.w);
  ((ushort4*)(ab   + (size_t)c * Ddim))[t] = oa;
  ((ushort4*)(pbuf + (size_t)c * Ddim))[t] = op;
}

// ---------------- fused dual-GEMM + epilogue ----------------
// 128x128 tile, BK=32, 4 waves (2x2 of 64x64), double-buffered LDS,
// depth-2 counted-vmcnt pipeline: 12 loads in flight, wait vmcnt(6) per phase.

#define WAITVM6_BARRIER() do {                                   \
    asm volatile("s_waitcnt vmcnt(6)" ::: "memory");             \
    __builtin_amdgcn_sched_barrier(0);                           \
    __builtin_amdgcn_s_barrier();                                \
    __builtin_amdgcn_sched_barrier(0);                           \
  } while (0)

#define WAITVM0_BARRIER() do {                                   \
    asm volatile("s_waitcnt vmcnt(0)" ::: "memory");             \
    __builtin_amdgcn_sched_barrier(0);                           \
    __builtin_amdgcn_s_barrier();                                \
    __builtin_amdgcn_sched_barrier(0);                           \
  } while (0)

#define END_BARRIER() do {                                       \
    asm volatile("s_waitcnt lgkmcnt(0)" ::: "memory");           \
    __builtin_amdgcn_sched_barrier(0);                           \
    __builtin_amdgcn_s_barrier();                                \
    __builtin_amdgcn_sched_barrier(0);                           \
  } while (0)

__global__ __launch_bounds__(256, 2) void gemm_ep(
    const u16* __restrict__ xb, const u16* __restrict__ pb,
    const u16* __restrict__ ab, const float* __restrict__ x2g,
    const float* __restrict__ p2g, const float* __restrict__ pag,
    const float* __restrict__ ang, float* __restrict__ out) {
  __shared__ u16 Xs[2][4096];   // [buf][128 rows x 32 k], slot-swizzled
  __shared__ u16 Ps[2][4096];
  __shared__ u16 As[2][4096];

  const int t = threadIdx.x;
  const int rowBase = blockIdx.y * 128;
  const int colBase = blockIdx.x * 128;

  const int lane = t & 63;
  const int wid  = t >> 6;
  const int wr   = wid >> 1;     // wave row 0..1
  const int wc   = wid & 1;      // wave col 0..1

  // staging: thread t writes LDS linear slot (row=t>>2, slot=t&3); the data
  // that belongs there is k-chunk kc = slot ^ ((row>>1)&3)  (XOR involution).
  const int rx0 = t >> 2;
  const int kk  = (((t & 3) ^ ((rx0 >> 1) & 3))) * 8;
  const u16* xg = xb + (size_t)(rowBase + rx0) * Ddim + kk;
  const u16* pg = pb + (size_t)(colBase + rx0) * Ddim + kk;
  const u16* ag = ab + (size_t)(colBase + rx0) * Ddim + kk;
  const size_t half = (size_t)64 * Ddim;
  const int d0 = t * 8;          // u16 offset of this thread's 16B slot
  const int d1 = 2048 + t * 8;

  // swizzled fragment base: want kc = lane>>4 -> read slot = kc ^ ((row>>1)&3)
  const int slot  = (lane >> 4) ^ (((lane & 15) >> 1) & 3);
  const int afrag = (wr * 64 + (lane & 15)) * 32 + slot * 8;
  const int bfrag = (wc * 64 + (lane & 15)) * 32 + slot * 8;

  f32x4 accP[4][4], accA[4][4];
  const f32x4 zero = {0.f, 0.f, 0.f, 0.f};
#pragma unroll
  for (int m = 0; m < 4; ++m)
#pragma unroll
    for (int n = 0; n < 4; ++n) { accP[m][n] = zero; accA[m][n] = zero; }

#define STAGE(b) do {                                            \
    gl_lds16(xg,        &Xs[b][d0]);                             \
    gl_lds16(xg + half, &Xs[b][d1]);                             \
    gl_lds16(pg,        &Ps[b][d0]);                             \
    gl_lds16(pg + half, &Ps[b][d1]);                             \
    gl_lds16(ag,        &As[b][d0]);                             \
    gl_lds16(ag + half, &As[b][d1]);                             \
    xg += 32; pg += 32; ag += 32;                                \
  } while (0)

#define COMPUTE(b) do {                                          \
    bf16x8 bp[4], ba[4];                                         \
    _Pragma("unroll")                                            \
    for (int n = 0; n < 4; ++n) {                                \
      bp[n] = *(const bf16x8*)&Ps[b][bfrag + n * 512];           \
      ba[n] = *(const bf16x8*)&As[b][bfrag + n * 512];           \
    }                                                            \
    __builtin_amdgcn_s_setprio(1);                               \
    _Pragma("unroll")                                            \
    for (int m = 0; m < 4; ++m) {                                \
      bf16x8 av = *(const bf16x8*)&Xs[b][afrag + m * 512];       \
      _Pragma("unroll")                                          \
      for (int n = 0; n < 4; ++n) {                              \
        accP[m][n] = __builtin_amdgcn_mfma_f32_16x16x32_bf16(av, bp[n], accP[m][n], 0, 0, 0); \
        accA[m][n] = __builtin_amdgcn_mfma_f32_16x16x32_bf16(av, ba[n], accA[m][n], 0, 0, 0); \
      }                                                          \
    }                                                            \
    __builtin_amdgcn_s_setprio(0);                               \
  } while (0)

  // prologue: 12 loads in flight (tiles 0 and 1)
  STAGE(0);
  STAGE(1);

  // main loop: computes tiles kt,kt+1; refills kt+2,kt+3. 15 iters -> tiles 0..29.
  for (int it = 0; it < 15; ++it) {
    WAITVM6_BARRIER();           // oldest 6 (this buf) retired on every wave
    COMPUTE(0);
    END_BARRIER();               // all ds_reads of buf0 retired by all waves
    STAGE(0);                    // refill buf0 (outstanding back to 12)

    WAITVM6_BARRIER();
    COMPUTE(1);
    END_BARRIER();
    STAGE(1);
  }
  // tail: tiles 30 (buf0), 31 (buf1); outstanding = 12 entering.
  WAITVM6_BARRIER();
  COMPUTE(0);
  WAITVM0_BARRIER();
  COMPUTE(1);

#undef STAGE
#undef COMPUTE

  // epilogue: C/D layout col = lane&15, row = (lane>>4)*4 + j
  // stats read directly from global (16KB arrays, L2-hot).
#pragma unroll
  for (int m = 0; m < 4; ++m) {
    const int rl0 = wr * 64 + m * 16 + (lane >> 4) * 4;
    float x2r[4];
#pragma unroll
    for (int j = 0; j < 4; ++j) x2r[j] = x2g[rowBase + rl0 + j];
#pragma unroll
    for (int n = 0; n < 4; ++n) {
      const int cl  = wc * 64 + n * 16 + (lane & 15);
      const float p2c = p2g[colBase + cl];
      const float pac = pag[colBase + cl];
      const float anc = ang[colBase + cl];
      const float Bcc = 1.0f - p2c;
      f32x4 px4 = accP[m][n];
      f32x4 xa4 = accA[m][n];
#pragma unroll
      for (int j = 0; j < 4; ++j) {
        const float px = px4[j];
        const float xa = xa4[j];
        const float Av  = 1.0f - 2.0f * px + x2r[j];
        const float den = fmaxf(1.0f - 2.0f * px + x2r[j] * p2c, EPSF);
        const float dn2 = fmaxf((Av * Av * p2c + Bcc * Bcc * x2r[j] - 2.0f * Av * Bcc * px) / (den * den), EPSF);
        const float sc  = (Bcc * xa - Av * pac) / den;
        const float dv  = fmaxf((1.0f + dn2) * anc, EPSF);   // always positive
        const float z   = (2.0f * sc) / dv;
        out[(size_t)(rowBase + rl0 + j) * Cdim + (colBase + cl)] = -asinhf(z);
      }
    }
  }
}

extern "C" void kernel_launch(void* const* d_in, const int* in_sizes, int n_in,
                              void* d_out, int out_size, void* d_ws, size_t ws_size,
                              hipStream_t stream) {
  const float* x = (const float*)d_in[0];
  const float* a = (const float*)d_in[1];
  const float* p = (const float*)d_in[2];
  float* out = (float*)d_out;

  char* ws = (char*)d_ws;
  u16* xb = (u16*)(ws);                                   // 8 MiB
  u16* pb = (u16*)(ws + (size_t)8 * 1024 * 1024);         // 8 MiB
  u16* ab = (u16*)(ws + (size_t)16 * 1024 * 1024);        // 8 MiB
  float* x2 = (float*)(ws + (size_t)24 * 1024 * 1024);    // 16 KiB
  float* p2 = x2 + Bdim;
  float* pa = p2 + Cdim;
  float* an = pa + Cdim;

  prep_x <<<Bdim, 256, 0, stream>>>(x, xb, x2);
  prep_pa<<<Cdim, 256, 0, stream>>>(a, p, ab, pb, p2, pa, an);
  gemm_ep<<<dim3(Cdim / 128, Bdim / 128), 256, 0, stream>>>(xb, pb, ab, x2, p2, pa, an, out);
}

// Round 5
// 164.478 us; speedup vs baseline: 1.7668x; 1.0030x over previous
//
#include <hip/hip_runtime.h>
#include <hip/hip_bf16.h>
#include <math.h>

// HyperbolicMLR: out[b,c] = -asinh( 2*sc_diff_a / ((1+diff_norm2)*|a_c|) )
// R5: single combined GEMM. B-panel PA[8192][1024] interleaves P and A rows in
// 16-row groups, so each wave's n-fragments alternate px/xa for the SAME output
// columns -> dual accumulator collapses to 16 frags (64 regs) -> 3 waves/SIMD.
// Keeps R4's XOR swizzle (conflicts==0) + counted-vmcnt depth-2 pipeline + T5.

#define EPSF 1e-15f
#define MAXN 0.99999f   // (1 - 1e-5) / sqrt(c), c = 1

constexpr int Bdim = 4096;
constexpr int Ddim = 1024;
constexpr int Cdim = 4096;

typedef __bf16 bf16x8 __attribute__((ext_vector_type(8)));
typedef float  f32x4  __attribute__((ext_vector_type(4)));
typedef unsigned short u16;

__device__ __forceinline__ u16 f2bf(float f) {
  __hip_bfloat16 h = __float2bfloat16(f);   // RNE
  return *reinterpret_cast<const u16*>(&h);
}

__device__ __forceinline__ void gl_lds16(const u16* g, u16* l) {
  __builtin_amdgcn_global_load_lds(
      (const __attribute__((address_space(1))) void*)g,
      (__attribute__((address_space(3))) void*)l, 16, 0, 0);
}

// ---------------- prep kernels ----------------

__global__ __launch_bounds__(256) void prep_x(const float* __restrict__ x,
                                              u16* __restrict__ xb,
                                              float* __restrict__ x2o) {
  const int b = blockIdx.x, t = threadIdx.x;
  float4 v = ((const float4*)(x + (size_t)b * Ddim))[t];
  float s = v.x * v.x + v.y * v.y + v.z * v.z + v.w * v.w;
  __shared__ float red[4];
#pragma unroll
  for (int o = 32; o > 0; o >>= 1) s += __shfl_down(s, o);
  if ((t & 63) == 0) red[t >> 6] = s;
  __syncthreads();
  s = red[0] + red[1] + red[2] + red[3];
  float norm  = sqrtf(s);
  float xn    = fmaxf(norm, EPSF);
  float scale = (xn > MAXN) ? (MAXN / xn) : 1.0f;
  if (t == 0) x2o[b] = s * scale * scale;
  ushort4 o4;
  o4.x = f2bf(v.x * scale); o4.y = f2bf(v.y * scale);
  o4.z = f2bf(v.z * scale); o4.w = f2bf(v.w * scale);
  ((ushort4*)(xb + (size_t)b * Ddim))[t] = o4;
}

// Writes P row c -> PA row ((c>>4)<<5)+(c&15); A row c -> +16 (16-row interleave).
__global__ __launch_bounds__(256) void prep_pa(const float* __restrict__ a,
                                               const float* __restrict__ p,
                                               u16* __restrict__ pab,
                                               float* __restrict__ p2o,
                                               float* __restrict__ pao,
                                               float* __restrict__ ano) {
  const int c = blockIdx.x, t = threadIdx.x;
  float4 av = ((const float4*)(a + (size_t)c * Ddim))[t];
  float4 pv = ((const float4*)(p + (size_t)c * Ddim))[t];
  float sp2 = pv.x * pv.x + pv.y * pv.y + pv.z * pv.z + pv.w * pv.w;
  float spa = pv.x * av.x + pv.y * av.y + pv.z * av.z + pv.w * av.w;
  float sa2 = av.x * av.x + av.y * av.y + av.z * av.z + av.w * av.w;
  __shared__ float red[12];
#pragma unroll
  for (int o = 32; o > 0; o >>= 1) {
    sp2 += __shfl_down(sp2, o);
    spa += __shfl_down(spa, o);
    sa2 += __shfl_down(sa2, o);
  }
  if ((t & 63) == 0) { int w = t >> 6; red[w] = sp2; red[4 + w] = spa; red[8 + w] = sa2; }
  __syncthreads();
  if (t == 0) {
    p2o[c] = red[0] + red[1] + red[2] + red[3];
    pao[c] = red[4] + red[5] + red[6] + red[7];
    ano[c] = sqrtf(red[8] + red[9] + red[10] + red[11]);
  }
  const int prP = ((c >> 4) << 5) + (c & 15);
  ushort4 oa, op;
  oa.x = f2bf(av.x); oa.y = f2bf(av.y); oa.z = f2bf(av.z); oa.w = f2bf(av.w);
  op.x = f2bf(pv.x); op.y = f2bf(pv.y); op.z = f2bf(pv.z); op.w = f2bf(pv.w);
  ((ushort4*)(pab + (size_t)prP * Ddim))[t]        = op;
  ((ushort4*)(pab + (size_t)(prP + 16) * Ddim))[t] = oa;
}

// ---------------- fused GEMM + epilogue ----------------
// 128(x-rows) x 128(PA-cols) tile, BK=32, 4 waves (2x2 of 64x64),
// double-buffered LDS, counted-vmcnt depth-2 pipeline (8 in flight, wait 4).

#define WAITVM4_BARRIER() do {                                   \
    asm volatile("s_waitcnt vmcnt(4)" ::: "memory");             \
    __builtin_amdgcn_sched_barrier(0);                           \
    __builtin_amdgcn_s_barrier();                                \
    __builtin_amdgcn_sched_barrier(0);                           \
  } while (0)

#define WAITVM0_BARRIER() do {                                   \
    asm volatile("s_waitcnt vmcnt(0)" ::: "memory");             \
    __builtin_amdgcn_sched_barrier(0);                           \
    __builtin_amdgcn_s_barrier();                                \
    __builtin_amdgcn_sched_barrier(0);                           \
  } while (0)

#define END_BARRIER() do {                                       \
    asm volatile("s_waitcnt lgkmcnt(0)" ::: "memory");           \
    __builtin_amdgcn_sched_barrier(0);                           \
    __builtin_amdgcn_s_barrier();                                \
    __builtin_amdgcn_sched_barrier(0);                           \
  } while (0)

__global__ __launch_bounds__(256, 3) void gemm_ep(
    const u16* __restrict__ xb, const u16* __restrict__ pab,
    const float* __restrict__ x2g, const float* __restrict__ p2g,
    const float* __restrict__ pag, const float* __restrict__ ang,
    float* __restrict__ out) {
  __shared__ u16 Xs[2][4096];    // [buf][128 rows x 32 k], slot-swizzled
  __shared__ u16 PAs[2][4096];

  const int t = threadIdx.x;
  const int rowBase  = blockIdx.y * 128;   // X rows (B-dim)
  const int pcolBase = blockIdx.x * 128;   // PA rows (interleaved col-dim)

  const int lane = t & 63;
  const int wid  = t >> 6;
  const int wr   = wid >> 1;     // wave row 0..1
  const int wc   = wid & 1;      // wave col 0..1

  // staging: thread t writes LDS linear slot (row=t>>2, slot=t&3); data there
  // is k-chunk kc = slot ^ ((row>>1)&3) (XOR involution; rule 21 both-sides).
  const int rx0 = t >> 2;
  const int kk  = (((t & 3) ^ ((rx0 >> 1) & 3))) * 8;
  const u16* xg = xb  + (size_t)(rowBase  + rx0) * Ddim + kk;
  const u16* pg = pab + (size_t)(pcolBase + rx0) * Ddim + kk;
  const size_t half = (size_t)64 * Ddim;
  const int d0 = t * 8;          // u16 offset of this thread's 16B slot
  const int d1 = 2048 + t * 8;

  // swizzled fragment base: want kc = lane>>4 -> read slot = kc ^ ((row>>1)&3)
  const int slot  = (lane >> 4) ^ (((lane & 15) >> 1) & 3);
  const int afrag = (wr * 64 + (lane & 15)) * 32 + slot * 8;
  const int bfrag = (wc * 64 + (lane & 15)) * 32 + slot * 8;

  f32x4 acc[4][4];
  const f32x4 zero = {0.f, 0.f, 0.f, 0.f};
#pragma unroll
  for (int m = 0; m < 4; ++m)
#pragma unroll
    for (int n = 0; n < 4; ++n) acc[m][n] = zero;

#define STAGE(b) do {                                            \
    gl_lds16(xg,        &Xs[b][d0]);                             \
    gl_lds16(xg + half, &Xs[b][d1]);                             \
    gl_lds16(pg,        &PAs[b][d0]);                            \
    gl_lds16(pg + half, &PAs[b][d1]);                            \
    xg += 32; pg += 32;                                          \
  } while (0)

#define COMPUTE(b) do {                                          \
    bf16x8 bv[4];                                                \
    _Pragma("unroll")                                            \
    for (int n = 0; n < 4; ++n)                                  \
      bv[n] = *(const bf16x8*)&PAs[b][bfrag + n * 512];          \
    __builtin_amdgcn_s_setprio(1);                               \
    _Pragma("unroll")                                            \
    for (int m = 0; m < 4; ++m) {                                \
      bf16x8 av = *(const bf16x8*)&Xs[b][afrag + m * 512];       \
      _Pragma("unroll")                                          \
      for (int n = 0; n < 4; ++n)                                \
        acc[m][n] = __builtin_amdgcn_mfma_f32_16x16x32_bf16(av, bv[n], acc[m][n], 0, 0, 0); \
    }                                                            \
    __builtin_amdgcn_s_setprio(0);                               \
  } while (0)

  // prologue: 8 loads in flight (tiles 0 and 1)
  STAGE(0);
  STAGE(1);

  // main loop: 15 iters compute tiles 0..29, refill 2..31.
  for (int it = 0; it < 15; ++it) {
    WAITVM4_BARRIER();           // oldest 4 (buf0's) retired on every wave
    COMPUTE(0);
    END_BARRIER();               // all ds_reads of buf0 retired by all waves
    STAGE(0);

    WAITVM4_BARRIER();
    COMPUTE(1);
    END_BARRIER();
    STAGE(1);
  }
  // tail: tiles 30 (buf0), 31 (buf1)
  WAITVM4_BARRIER();
  COMPUTE(0);
  WAITVM0_BARRIER();
  COMPUTE(1);

#undef STAGE
#undef COMPUTE

  // epilogue: C/D layout col = lane&15, row = (lane>>4)*4 + j.
  // Fragment n even -> px, n odd -> xa, same 16 output cols per (even,odd) pair.
  // Original col: cl = bx*64 + wc*32 + g*16 + (lane&15), g = n>>1.
#pragma unroll
  for (int m = 0; m < 4; ++m) {
    const int rl0 = wr * 64 + m * 16 + (lane >> 4) * 4;
    float x2r[4];
#pragma unroll
    for (int j = 0; j < 4; ++j) x2r[j] = x2g[rowBase + rl0 + j];
#pragma unroll
    for (int g = 0; g < 2; ++g) {
      const int cl = blockIdx.x * 64 + wc * 32 + g * 16 + (lane & 15);
      const float p2c = p2g[cl];
      const float pac = pag[cl];
      const float anc = ang[cl];
      const float Bcc = 1.0f - p2c;
      f32x4 px4 = acc[m][2 * g];
      f32x4 xa4 = acc[m][2 * g + 1];
#pragma unroll
      for (int j = 0; j < 4; ++j) {
        const float px = px4[j];
        const float xa = xa4[j];
        const float Av  = 1.0f - 2.0f * px + x2r[j];
        const float den = fmaxf(1.0f - 2.0f * px + x2r[j] * p2c, EPSF);
        const float dn2 = fmaxf((Av * Av * p2c + Bcc * Bcc * x2r[j] - 2.0f * Av * Bcc * px) / (den * den), EPSF);
        const float sc  = (Bcc * xa - Av * pac) / den;
        const float dv  = fmaxf((1.0f + dn2) * anc, EPSF);   // always positive
        const float z   = (2.0f * sc) / dv;
        out[(size_t)(rowBase + rl0 + j) * Cdim + cl] = -asinhf(z);
      }
    }
  }
}

extern "C" void kernel_launch(void* const* d_in, const int* in_sizes, int n_in,
                              void* d_out, int out_size, void* d_ws, size_t ws_size,
                              hipStream_t stream) {
  const float* x = (const float*)d_in[0];
  const float* a = (const float*)d_in[1];
  const float* p = (const float*)d_in[2];
  float* out = (float*)d_out;

  char* ws = (char*)d_ws;
  u16* xb  = (u16*)(ws);                                  // 8 MiB
  u16* pab = (u16*)(ws + (size_t)8 * 1024 * 1024);        // 16 MiB (8192 x 1024 bf16)
  float* x2 = (float*)(ws + (size_t)24 * 1024 * 1024);    // stats
  float* p2 = x2 + Bdim;
  float* pa = p2 + Cdim;
  float* an = pa + Cdim;

  prep_x <<<Bdim, 256, 0, stream>>>(x, xb, x2);
  prep_pa<<<Cdim, 256, 0, stream>>>(a, p, pab, p2, pa, an);
  gemm_ep<<<dim3(2 * Cdim / 128, Bdim / 128), 256, 0, stream>>>(xb, pab, x2, p2, pa, an, out);
}

// Round 6
// 125.547 us; speedup vs baseline: 2.3147x; 1.3101x over previous
//
#include <hip/hip_runtime.h>
#include <hip/hip_bf16.h>
#include <math.h>

// HyperbolicMLR: out[b,c] = -asinh( 2*sc_diff_a / ((1+diff_norm2)*|a_c|) )
// R6: 256x256x(BK=64) 8-phase schedule (m201 port). 512 thr / 8 waves (2x4),
// acc[8][4], LDS 128KB = 2 K-tile bufs x 2 k-half subtiles (64-B rows keep
// R5's proven 0-conflict swizzle). 1 half-unit staged per phase, vmcnt(4)
// gate every 2 phases. XCD-swizzled grid. Poly asinh fast path.

#define EPSF 1e-15f
#define MAXN 0.99999f   // (1 - 1e-5) / sqrt(c), c = 1

constexpr int Bdim = 4096;
constexpr int Ddim = 1024;
constexpr int Cdim = 4096;

typedef __bf16 bf16x8 __attribute__((ext_vector_type(8)));
typedef float  f32x4  __attribute__((ext_vector_type(4)));
typedef unsigned short u16;

__device__ __forceinline__ u16 f2bf(float f) {
  __hip_bfloat16 h = __float2bfloat16(f);   // RNE
  return *reinterpret_cast<const u16*>(&h);
}

__device__ __forceinline__ void gl_lds16(const u16* g, u16* l) {
  __builtin_amdgcn_global_load_lds(
      (const __attribute__((address_space(1))) void*)g,
      (__attribute__((address_space(3))) void*)l, 16, 0, 0);
}

// ---------------- prep kernels (unchanged, proven) ----------------

__global__ __launch_bounds__(256) void prep_x(const float* __restrict__ x,
                                              u16* __restrict__ xb,
                                              float* __restrict__ x2o) {
  const int b = blockIdx.x, t = threadIdx.x;
  float4 v = ((const float4*)(x + (size_t)b * Ddim))[t];
  float s = v.x * v.x + v.y * v.y + v.z * v.z + v.w * v.w;
  __shared__ float red[4];
#pragma unroll
  for (int o = 32; o > 0; o >>= 1) s += __shfl_down(s, o);
  if ((t & 63) == 0) red[t >> 6] = s;
  __syncthreads();
  s = red[0] + red[1] + red[2] + red[3];
  float norm  = sqrtf(s);
  float xn    = fmaxf(norm, EPSF);
  float scale = (xn > MAXN) ? (MAXN / xn) : 1.0f;
  if (t == 0) x2o[b] = s * scale * scale;
  ushort4 o4;
  o4.x = f2bf(v.x * scale); o4.y = f2bf(v.y * scale);
  o4.z = f2bf(v.z * scale); o4.w = f2bf(v.w * scale);
  ((ushort4*)(xb + (size_t)b * Ddim))[t] = o4;
}

// P row c -> PA row ((c>>4)<<5)+(c&15); A row c -> +16 (16-row interleave).
__global__ __launch_bounds__(256) void prep_pa(const float* __restrict__ a,
                                               const float* __restrict__ p,
                                               u16* __restrict__ pab,
                                               float* __restrict__ p2o,
                                               float* __restrict__ pao,
                                               float* __restrict__ ano) {
  const int c = blockIdx.x, t = threadIdx.x;
  float4 av = ((const float4*)(a + (size_t)c * Ddim))[t];
  float4 pv = ((const float4*)(p + (size_t)c * Ddim))[t];
  float sp2 = pv.x * pv.x + pv.y * pv.y + pv.z * pv.z + pv.w * pv.w;
  float spa = pv.x * av.x + pv.y * av.y + pv.z * av.z + pv.w * av.w;
  float sa2 = av.x * av.x + av.y * av.y + av.z * av.z + av.w * av.w;
  __shared__ float red[12];
#pragma unroll
  for (int o = 32; o > 0; o >>= 1) {
    sp2 += __shfl_down(sp2, o);
    spa += __shfl_down(spa, o);
    sa2 += __shfl_down(sa2, o);
  }
  if ((t & 63) == 0) { int w = t >> 6; red[w] = sp2; red[4 + w] = spa; red[8 + w] = sa2; }
  __syncthreads();
  if (t == 0) {
    p2o[c] = red[0] + red[1] + red[2] + red[3];
    pao[c] = red[4] + red[5] + red[6] + red[7];
    ano[c] = sqrtf(red[8] + red[9] + red[10] + red[11]);
  }
  const int prP = ((c >> 4) << 5) + (c & 15);
  ushort4 oa, op;
  oa.x = f2bf(av.x); oa.y = f2bf(av.y); oa.z = f2bf(av.z); oa.w = f2bf(av.w);
  op.x = f2bf(pv.x); op.y = f2bf(pv.y); op.z = f2bf(pv.z); op.w = f2bf(pv.w);
  ((ushort4*)(pab + (size_t)prP * Ddim))[t]        = op;
  ((ushort4*)(pab + (size_t)(prP + 16) * Ddim))[t] = oa;
}

// ---------------- 8-phase fused GEMM + epilogue ----------------

#define LGKM_BAR() do {                                          \
    asm volatile("s_waitcnt lgkmcnt(0)" ::: "memory");           \
    __builtin_amdgcn_s_barrier();                                \
    __builtin_amdgcn_sched_barrier(0);                           \
  } while (0)

__global__ __launch_bounds__(512, 2) void gemm_ep(
    const u16* __restrict__ xb, const u16* __restrict__ pab,
    const float* __restrict__ x2g, const float* __restrict__ p2g,
    const float* __restrict__ pag, const float* __restrict__ ang,
    float* __restrict__ out) {
  // [buf][k-half][256 rows x 32 u16] ; 64-B rows (R5-proven swizzle geometry)
  __shared__ u16 Xs[2][2][8192];     // 64 KiB
  __shared__ u16 PAs[2][2][8192];    // 64 KiB

  const int t = threadIdx.x;         // 0..511

  // XCD-aware bijective swizzle: 512 blocks = 8 chunks x 64
  const int flat  = blockIdx.y * 32 + blockIdx.x;
  const int swz   = (flat & 7) * 64 + (flat >> 3);
  const int chunk = swz >> 6;                 // 0..7
  const int local = swz & 63;
  const int bx = chunk * 4 + (local & 3);     // 0..31  PA col-group
  const int by = local >> 2;                  // 0..15  X row-group

  const int lane = t & 63;
  const int wid  = t >> 6;       // 0..7
  const int wr   = wid >> 2;     // 0..1  (row half: 128 rows)
  const int wc   = wid & 3;      // 0..3  (PA quarter: 64 rows)

  // ---- staging mapping: thread t covers (r0 = t>>2, slot = t&3) of a
  // 128-row sub-unit; source k-chunk pre-swizzled (XOR involution).
  const int r0  = t >> 2;                              // 0..127
  const int sw8 = ((t & 3) ^ ((r0 >> 1) & 3)) * 8;     // u16
  const u16* xsrc  = xb  + (size_t)(by * 256 + r0) * Ddim + sw8;
  const u16* pasrc = pab + (size_t)(bx * 256 + r0) * Ddim + sw8;
  const int t8 = t * 8;
  const size_t half = (size_t)128 * Ddim;

  // ---- fragment read offsets (per sub-tile, u16 units)
  // row stride 32 u16; slot = (lane>>4) ^ ((row>>1)&3); mf/nf step = 512.
  const int arow = wr * 128 + (lane & 15);
  const int brow = wc * 64  + (lane & 15);
  const int aoff = arow * 32 + (((lane >> 4) ^ ((arow >> 1) & 3)) * 8);
  const int boff = brow * 32 + (((lane >> 4) ^ ((brow >> 1) & 3)) * 8);

  f32x4 acc[8][4];
  const f32x4 zero = {0.f, 0.f, 0.f, 0.f};
#pragma unroll
  for (int m = 0; m < 8; ++m)
#pragma unroll
    for (int n = 0; n < 4; ++n) acc[m][n] = zero;

  bf16x8 bv[4];

#define LOADBV(PR, XB) do {                                      \
    _Pragma("unroll")                                            \
    for (int nf = 0; nf < 4; ++nf)                               \
      bv[nf] = *(const bf16x8*)&(PR)[(XB) + boff + nf * 512];    \
  } while (0)

#define QUAD(XR, ABASE, XB) do {                                 \
    bf16x8 a0 = *(const bf16x8*)&(XR)[(XB) + aoff];              \
    bf16x8 a1 = *(const bf16x8*)&(XR)[(XB) + aoff + 512];        \
    bf16x8 a2 = *(const bf16x8*)&(XR)[(XB) + aoff + 1024];       \
    bf16x8 a3 = *(const bf16x8*)&(XR)[(XB) + aoff + 1536];       \
    __builtin_amdgcn_s_setprio(1);                               \
    _Pragma("unroll")                                            \
    for (int nf = 0; nf < 4; ++nf) {                             \
      acc[(ABASE)+0][nf] = __builtin_amdgcn_mfma_f32_16x16x32_bf16(a0, bv[nf], acc[(ABASE)+0][nf], 0, 0, 0); \
      acc[(ABASE)+1][nf] = __builtin_amdgcn_mfma_f32_16x16x32_bf16(a1, bv[nf], acc[(ABASE)+1][nf], 0, 0, 0); \
      acc[(ABASE)+2][nf] = __builtin_amdgcn_mfma_f32_16x16x32_bf16(a2, bv[nf], acc[(ABASE)+2][nf], 0, 0, 0); \
      acc[(ABASE)+3][nf] = __builtin_amdgcn_mfma_f32_16x16x32_bf16(a3, bv[nf], acc[(ABASE)+3][nf], 0, 0, 0); \
    }                                                            \
    __builtin_amdgcn_s_setprio(0);                               \
  } while (0)

  // running source pointers for the NEXT tile (tile 1 first)
  const u16* xgp = xsrc  + 64;
  const u16* pgp = pasrc + 64;

  // ---- prologue: stage tile 0 fully, FIFO {X.k0, PA.k0, X.k1, PA.k1}
  {
    u16* Xw  = (u16*)&Xs[0][0][0];
    u16* PAw = (u16*)&PAs[0][0][0];
    gl_lds16(xsrc,             Xw + t8);
    gl_lds16(xsrc + half,      Xw + 4096 + t8);
    gl_lds16(pasrc,            PAw + t8);
    gl_lds16(pasrc + half,     PAw + 4096 + t8);
    gl_lds16(xsrc + 32,        Xw + 8192 + t8);
    gl_lds16(xsrc + half + 32, Xw + 8192 + 4096 + t8);
    gl_lds16(pasrc + 32,       PAw + 8192 + t8);
    gl_lds16(pasrc + half + 32,PAw + 8192 + 4096 + t8);
  }
  asm volatile("s_waitcnt vmcnt(4)" ::: "memory");   // k0 units retired
  __builtin_amdgcn_s_barrier();
  __builtin_amdgcn_sched_barrier(0);

  // ---- main loop: tiles 0..14, staging tile T+1 (1 half-unit per phase)
  for (int T = 0; T < 15; ++T) {
    const int b = T & 1;
    const u16* Xr  = &Xs[b][0][0];
    const u16* PAr = &PAs[b][0][0];
    u16* Xw  = (u16*)&Xs[b ^ 1][0][0];
    u16* PAw = (u16*)&PAs[b ^ 1][0][0];

    // q1: k-slice 0, m-half A  | stage X.k0(T+1)
    gl_lds16(xgp,        Xw + t8);
    gl_lds16(xgp + half, Xw + 4096 + t8);
    LOADBV(PAr, 0);
    QUAD(Xr, 0, 0);
    LGKM_BAR();

    // q2: k0, m-half B  | stage PA.k0(T+1) | gate: k1(T) must retire
    gl_lds16(pgp,        PAw + t8);
    gl_lds16(pgp + half, PAw + 4096 + t8);
    QUAD(Xr, 4, 2048);
    asm volatile("s_waitcnt vmcnt(4)" ::: "memory");
    LGKM_BAR();

    // q3: k1, m-half A  | stage X.k1(T+1)
    gl_lds16(xgp + 32,        Xw + 8192 + t8);
    gl_lds16(xgp + half + 32, Xw + 8192 + 4096 + t8);
    LOADBV(PAr, 8192);
    QUAD(Xr, 0, 8192);
    LGKM_BAR();

    // q4: k1, m-half B  | stage PA.k1(T+1) | gate: k0(T+1) must retire
    gl_lds16(pgp + 32,        PAw + 8192 + t8);
    gl_lds16(pgp + half + 32, PAw + 8192 + 4096 + t8);
    QUAD(Xr, 4, 8192 + 2048);
    xgp += 64; pgp += 64;
    asm volatile("s_waitcnt vmcnt(4)" ::: "memory");
    LGKM_BAR();
  }

  // ---- tile 15 (buf 1), no staging
  {
    const u16* Xr  = &Xs[1][0][0];
    const u16* PAr = &PAs[1][0][0];
    LOADBV(PAr, 0);
    QUAD(Xr, 0, 0);
    LGKM_BAR();
    QUAD(Xr, 4, 2048);
    asm volatile("s_waitcnt vmcnt(0)" ::: "memory");  // k1(15) retired
    LGKM_BAR();
    LOADBV(PAr, 8192);
    QUAD(Xr, 0, 8192);
    LGKM_BAR();
    QUAD(Xr, 4, 8192 + 2048);
  }

#undef LOADBV
#undef QUAD

  // ---- epilogue: C/D layout col = lane&15, row = (lane>>4)*4 + j.
  // n even -> px, n odd -> xa, same 16 output cols per (even,odd) pair.
#pragma unroll
  for (int m = 0; m < 8; ++m) {
    const int rl0 = by * 256 + wr * 128 + m * 16 + (lane >> 4) * 4;
    float x2r[4];
#pragma unroll
    for (int j = 0; j < 4; ++j) x2r[j] = x2g[rl0 + j];
#pragma unroll
    for (int g = 0; g < 2; ++g) {
      const int cl = (bx * 8 + wc * 2 + g) * 16 + (lane & 15);
      const float p2c = p2g[cl];
      const float pac = pag[cl];
      const float anc = ang[cl];
      const float Bcc = 1.0f - p2c;
      f32x4 px4 = acc[m][2 * g];
      f32x4 xa4 = acc[m][2 * g + 1];
#pragma unroll
      for (int j = 0; j < 4; ++j) {
        const float px = px4[j];
        const float xa = xa4[j];
        const float Av  = 1.0f - 2.0f * px + x2r[j];
        const float den = fmaxf(1.0f - 2.0f * px + x2r[j] * p2c, EPSF);
        const float dn2 = fmaxf((Av * Av * p2c + Bcc * Bcc * x2r[j] - 2.0f * Av * Bcc * px) / (den * den), EPSF);
        const float sc  = (Bcc * xa - Av * pac) / den;
        const float dv  = fmaxf((1.0f + dn2) * anc, EPSF);
        const float z   = (2.0f * sc) / dv;
        // asinh: |z| <= ~0.13 on this data -> odd poly (err < 1e-6); exact fallback.
        const float z2 = z * z;
        float r;
        if (z2 > 0.04f) r = asinhf(z);
        else            r = z * (1.0f - z2 * (1.0f / 6.0f) + z2 * z2 * 0.075f);
        out[(size_t)rl0 * Cdim + j * Cdim + cl] = -r;
      }
    }
  }
}

extern "C" void kernel_launch(void* const* d_in, const int* in_sizes, int n_in,
                              void* d_out, int out_size, void* d_ws, size_t ws_size,
                              hipStream_t stream) {
  const float* x = (const float*)d_in[0];
  const float* a = (const float*)d_in[1];
  const float* p = (const float*)d_in[2];
  float* out = (float*)d_out;

  char* ws = (char*)d_ws;
  u16* xb  = (u16*)(ws);                                  // 8 MiB
  u16* pab = (u16*)(ws + (size_t)8 * 1024 * 1024);        // 16 MiB
  float* x2 = (float*)(ws + (size_t)24 * 1024 * 1024);    // stats
  float* p2 = x2 + Bdim;
  float* pa = p2 + Cdim;
  float* an = pa + Cdim;

  prep_x <<<Bdim, 256, 0, stream>>>(x, xb, x2);
  prep_pa<<<Cdim, 256, 0, stream>>>(a, p, pab, p2, pa, an);
  gemm_ep<<<dim3(32, 16), 512, 0, stream>>>(xb, pab, x2, p2, pa, an, out);
}